// Round 2
// baseline (207.076 us; speedup 1.0000x reference)
//
#include <hip/hip_runtime.h>
#include <math.h>

// Problem constants (reference: B=1024, C=10, H=30, W=30)
constexpr int BATCH  = 1024;
constexpr int NC     = 10;     // n_colors / channels
constexpr int HW     = 900;    // 30*30 pixels per image
constexpr int GROUPS = HW / 4; // 225 float4 pixel-groups per image

// Workspace layout (floats): acc[0..4] accumulators, acc[5] = done-counter.
//   acc[0] = sum of weighted CE over all pixels
//   acc[1] = count of exact-match images
//   acc[2] = count of (should_not_copy && did_copy) images
//   acc[3] = sum over images of ((changed - target_changed)/900)^2
//   acc[4] = total missing colors (tgt_present & !pred_present)
//
// One block per image; 256 threads; t<225 own 4 consecutive pixels (float4).
// Single pass over channels with ONLINE log-sum-exp + argmaxes so per-pixel
// state is 8 regs (no big array -> no rematerialized reloads). Last block to
// finish does the finalize (device-scope atomics + threadfence).
__global__ __launch_bounds__(256, 2) void loss_main(
    const float* __restrict__ pred, const float* __restrict__ target,
    const float* __restrict__ inp, float* __restrict__ acc,
    float* __restrict__ out) {
  const int b = blockIdx.x;
  const int t = threadIdx.x;

  float ce_sum = 0.f;
  unsigned combo = 0;  // bits 0-9 pred-present, 10-19 tgt-present,
                       // 20 any(pred!=tgt), 21 any(tgt!=inp), 22 any(pred!=inp)
  int counts = 0;      // changed + (tchanged<<16)

  if (t < GROUPS) {
    const float* p = pred   + (size_t)b * NC * HW + (size_t)t * 4;
    const float* tg = target + (size_t)b * NC * HW + (size_t)t * 4;
    const float* g = inp    + (size_t)b * NC * HW + (size_t)t * 4;

    // Online state per pixel j: m (pred running max), s (sum exp(v-m)),
    // pidx, tmax, tidx, ptv (pred value at tidx), gmax, gidx.
    float m[4], s[4], tmax[4], ptv[4], gmax[4];
    int pidx[4], tidx[4], gidx[4];
    {
      const float4 p4 = *(const float4*)p;
      const float4 t4 = *(const float4*)tg;
      const float4 g4 = *(const float4*)g;
      const float pc[4] = {p4.x, p4.y, p4.z, p4.w};
      const float tc[4] = {t4.x, t4.y, t4.z, t4.w};
      const float gc[4] = {g4.x, g4.y, g4.z, g4.w};
#pragma unroll
      for (int j = 0; j < 4; ++j) {
        m[j] = pc[j]; s[j] = 1.0f; pidx[j] = 0;
        tmax[j] = tc[j]; tidx[j] = 0; ptv[j] = pc[j];
        gmax[j] = gc[j]; gidx[j] = 0;
      }
    }
#pragma unroll
    for (int c = 1; c < NC; ++c) {
      const float4 p4 = *(const float4*)(p + c * HW);
      const float4 t4 = *(const float4*)(tg + c * HW);
      const float4 g4 = *(const float4*)(g + c * HW);
      const float pc[4] = {p4.x, p4.y, p4.z, p4.w};
      const float tc[4] = {t4.x, t4.y, t4.z, t4.w};
      const float gc[4] = {g4.x, g4.y, g4.z, g4.w};
#pragma unroll
      for (int j = 0; j < 4; ++j) {
        const float v = pc[j];
        const float mn = fmaxf(m[j], v);
        // branchless online logsumexp (strict > keeps first-index argmax)
        s[j] = s[j] * __expf(m[j] - mn) + __expf(v - mn);
        if (v > m[j]) pidx[j] = c;
        m[j] = mn;
        if (tc[j] > tmax[j]) { tmax[j] = tc[j]; tidx[j] = c; ptv[j] = v; }
        if (gc[j] > gmax[j]) { gmax[j] = gc[j]; gidx[j] = c; }
      }
    }
#pragma unroll
    for (int j = 0; j < 4; ++j) {
      const float ce = (m[j] + __logf(s[j])) - ptv[j];
      const int pi = pidx[j], ti = tidx[j], gi = gidx[j];
      const float w = (pi != ti) ? 5.0f : 1.0f; // 1 + 4*incorrect
      ce_sum += ce * w;
      combo |= (1u << pi) | (1u << (10 + ti));
      combo |= (pi != ti) ? (1u << 20) : 0u;
      combo |= (ti != gi) ? (1u << 21) : 0u;
      combo |= (pi != gi) ? (1u << 22) : 0u;
      counts += (pi != gi) ? 1 : 0;
      counts += (ti != gi) ? (1 << 16) : 0;
    }
  }

  // Wave(64) reduction: 3 quantities
#pragma unroll
  for (int off = 32; off >= 1; off >>= 1) {
    ce_sum += __shfl_down(ce_sum, off);
    combo  |= __shfl_down(combo, off);
    counts += __shfl_down(counts, off);
  }

  __shared__ float s_ce[4];
  __shared__ unsigned s_or[4];
  __shared__ int s_cnt[4];
  const int wave = t >> 6;
  if ((t & 63) == 0) { s_ce[wave] = ce_sum; s_or[wave] = combo; s_cnt[wave] = counts; }
  __syncthreads();
  if (t == 0) {
    float ce = s_ce[0] + s_ce[1] + s_ce[2] + s_ce[3];
    const unsigned orv = s_or[0] | s_or[1] | s_or[2] | s_or[3];
    const int cnt = s_cnt[0] + s_cnt[1] + s_cnt[2] + s_cnt[3];
    const int changed = cnt & 0xFFFF, tchanged = cnt >> 16;
    const int all_pt = !(orv & (1u << 20));
    const int any_ti = (orv >> 21) & 1;
    const int all_pi = !(orv & (1u << 22));
    const unsigned pm = orv & 0x3FFu, tm = (orv >> 10) & 0x3FFu;

    atomicAdd(&acc[0], ce);
    atomicAdd(&acc[1], (float)all_pt);
    atomicAdd(&acc[2], (float)(any_ti & all_pi));
    const float d = (float)(changed - tchanged) * (1.0f / (float)HW);
    atomicAdd(&acc[3], d * d);
    atomicAdd(&acc[4], (float)__popc(tm & ~pm));

    __threadfence();
    const unsigned done = atomicAdd((unsigned*)&acc[5], 1u);
    if (done == (unsigned)(BATCH - 1)) {
      // Last block: all other blocks' atomics are globally visible.
      // Read back via device-scope RMWs (bypasses stale L1/regs).
      const float a0 = atomicAdd(&acc[0], 0.0f);
      const float a1 = atomicAdd(&acc[1], 0.0f);
      const float a2 = atomicAdd(&acc[2], 0.0f);
      const float a3 = atomicAdd(&acc[3], 0.0f);
      const float a4 = atomicAdd(&acc[4], 0.0f);
      const float ce_loss    = a0 * (1.0f / ((float)BATCH * (float)HW));
      const float exact_sum  = a1;
      const float exact_frac = exact_sum * (1.0f / (float)BATCH);
      const float copy_pen   = 5.0f * a2 * (1.0f / (float)BATCH);
      const float tdiff      = a3 * (1.0f / (float)BATCH);
      const float color_pen  = 0.1f * a4;
      float total = ce_loss - exact_frac + copy_pen + tdiff + color_pen;
      if (isnan(total)) total = 2.0f;
      else if (total > 100.0f) total = 10.0f;
      out[0] = total;
      out[1] = ce_loss;
      out[2] = copy_pen;
      out[3] = exact_frac;
      out[4] = exact_sum;
      out[5] = tdiff;
    }
  }
}

extern "C" void kernel_launch(void* const* d_in, const int* in_sizes, int n_in,
                              void* d_out, int out_size, void* d_ws, size_t ws_size,
                              hipStream_t stream) {
  const float* pred   = (const float*)d_in[0];
  const float* target = (const float*)d_in[1];
  const float* inp    = (const float*)d_in[2];
  float* acc = (float*)d_ws;
  // ws is re-poisoned to 0xAA before every launch — zero accumulators + counter.
  hipMemsetAsync(acc, 0, 6 * sizeof(float), stream);
  loss_main<<<dim3(BATCH), dim3(256), 0, stream>>>(pred, target, inp, acc,
                                                   (float*)d_out);
}

// Round 3
// 129.880 us; speedup vs baseline: 1.5944x; 1.5944x over previous
//
#include <hip/hip_runtime.h>
#include <math.h>

// Problem constants (reference: B=1024, C=10, H=30, W=30)
constexpr int BATCH = 1024;
constexpr int NC    = 10;   // n_colors / channels
constexpr int HW    = 900;  // 30*30 pixels per image
constexpr int PPB   = 225;  // pixels per block (4 blocks per image)

// Main kernel: one thread = one pixel. grid = BATCH*4 blocks of 256 threads
// (threads 225..255 idle). All 30 channel values (pred/target/input) are
// loaded into registers up-front -> maximal memory-level parallelism; the
// 10 exps of the log-sum-exp are independent (no online serial chain).
// Each block writes ONE float4 partial {ce_sum, or_mask, packed_counts, 0}
// to ws[blockIdx] with a plain store -- no atomics, no memset needed.
//
// or_mask bits: 0-9 pred-color-present, 10-19 tgt-color-present,
//              20 any(pred!=tgt), 21 any(tgt!=inp), 22 any(pred!=inp)
// packed_counts: changed + (tchanged<<16)
__global__ __launch_bounds__(256, 4) void loss_main(
    const float* __restrict__ pred, const float* __restrict__ target,
    const float* __restrict__ inp, float4* __restrict__ ws) {
  const int img  = blockIdx.x >> 2;
  const int part = blockIdx.x & 3;
  const int t    = threadIdx.x;

  float ce_sum = 0.f;
  unsigned combo = 0;
  int counts = 0;

  if (t < PPB) {
    const int q = part * PPB + t;               // pixel index in image
    const size_t base = (size_t)img * NC * HW + q;

    // ---- 30 independent loads, all issued before any use ----
    float p[NC], tv[NC], gv[NC];
#pragma unroll
    for (int c = 0; c < NC; ++c) p[c]  = pred[base + c * HW];
#pragma unroll
    for (int c = 0; c < NC; ++c) tv[c] = target[base + c * HW];
#pragma unroll
    for (int c = 0; c < NC; ++c) gv[c] = inp[base + c * HW];

    // ---- pred argmax (strict > = first-index tie-break) ----
    float pmax = p[0]; int pidx = 0;
#pragma unroll
    for (int c = 1; c < NC; ++c)
      if (p[c] > pmax) { pmax = p[c]; pidx = c; }

    // ---- stable log-sum-exp: 10 independent exps ----
    float s = 0.f;
#pragma unroll
    for (int c = 0; c < NC; ++c) s += __expf(p[c] - pmax);
    const float lse = pmax + __logf(s);

    // ---- target / input argmax ----
    float tmax = tv[0]; int tidx = 0;
#pragma unroll
    for (int c = 1; c < NC; ++c)
      if (tv[c] > tmax) { tmax = tv[c]; tidx = c; }
    float gmax = gv[0]; int gidx = 0;
#pragma unroll
    for (int c = 1; c < NC; ++c)
      if (gv[c] > gmax) { gmax = gv[c]; gidx = c; }

    // pred value at target index (cndmask chain)
    float ptv = p[0];
#pragma unroll
    for (int c = 1; c < NC; ++c)
      if (tidx == c) ptv = p[c];

    const float ce = lse - ptv;
    const float w  = (pidx != tidx) ? 5.0f : 1.0f;  // 1 + 4*incorrect
    ce_sum = ce * w;
    combo  = (1u << pidx) | (1u << (10 + tidx));
    if (pidx != tidx) combo |= 1u << 20;
    if (tidx != gidx) combo |= 1u << 21;
    if (pidx != gidx) combo |= 1u << 22;
    counts = ((pidx != gidx) ? 1 : 0) | ((tidx != gidx) ? (1 << 16) : 0);
  }

  // ---- wave(64) reduction of 3 quantities ----
#pragma unroll
  for (int off = 32; off >= 1; off >>= 1) {
    ce_sum += __shfl_down(ce_sum, off);
    combo  |= __shfl_down(combo, off);
    counts += __shfl_down(counts, off);
  }

  __shared__ float s_ce[4];
  __shared__ unsigned s_or[4];
  __shared__ int s_cnt[4];
  const int wave = t >> 6;
  if ((t & 63) == 0) { s_ce[wave] = ce_sum; s_or[wave] = combo; s_cnt[wave] = counts; }
  __syncthreads();
  if (t == 0) {
    float4 slot;
    slot.x = s_ce[0] + s_ce[1] + s_ce[2] + s_ce[3];
    slot.y = __uint_as_float(s_or[0] | s_or[1] | s_or[2] | s_or[3]);
    slot.z = __int_as_float(s_cnt[0] + s_cnt[1] + s_cnt[2] + s_cnt[3]);
    slot.w = 0.f;
    ws[blockIdx.x] = slot;
  }
}

// Finalize: single block, 1024 threads, thread b = image b. Combines the 4
// block-partials of its image, computes per-image terms, block-reduces the
// 5 global sums, thread 0 writes the 6 outputs.
__global__ __launch_bounds__(1024) void loss_final(
    const float4* __restrict__ ws, float* __restrict__ out) {
  const int b = threadIdx.x;

  float ce = 0.f; unsigned orv = 0; int cnt = 0;
#pragma unroll
  for (int k = 0; k < 4; ++k) {
    const float4 v = ws[b * 4 + k];
    ce  += v.x;
    orv |= __float_as_uint(v.y);
    cnt += __float_as_int(v.z);
  }
  const int changed  = cnt & 0xFFFF;
  const int tchanged = cnt >> 16;
  const float exact   = (orv & (1u << 20)) ? 0.f : 1.f;     // all(pred==tgt)
  const float any_ti  = (orv & (1u << 21)) ? 1.f : 0.f;     // any(tgt!=inp)
  const float all_pi  = (orv & (1u << 22)) ? 0.f : 1.f;     // all(pred==inp)
  const unsigned pm = orv & 0x3FFu, tm = (orv >> 10) & 0x3FFu;
  const float d = (float)(changed - tchanged) * (1.0f / (float)HW);

  float r_ce   = ce;                 // sum of weighted CE
  float r_ex   = exact;              // exact-match count
  float r_cp   = any_ti * all_pi;    // copy-penalty count
  float r_td   = d * d;              // transform-diff sum
  float r_mi   = (float)__popc(tm & ~pm);  // missing colors

#pragma unroll
  for (int off = 32; off >= 1; off >>= 1) {
    r_ce += __shfl_down(r_ce, off);
    r_ex += __shfl_down(r_ex, off);
    r_cp += __shfl_down(r_cp, off);
    r_td += __shfl_down(r_td, off);
    r_mi += __shfl_down(r_mi, off);
  }

  __shared__ float red[16][5];
  const int wave = b >> 6;
  if ((b & 63) == 0) {
    red[wave][0] = r_ce; red[wave][1] = r_ex; red[wave][2] = r_cp;
    red[wave][3] = r_td; red[wave][4] = r_mi;
  }
  __syncthreads();
  if (b == 0) {
    float a0 = 0, a1 = 0, a2 = 0, a3 = 0, a4 = 0;
#pragma unroll
    for (int w = 0; w < 16; ++w) {
      a0 += red[w][0]; a1 += red[w][1]; a2 += red[w][2];
      a3 += red[w][3]; a4 += red[w][4];
    }
    const float ce_loss    = a0 * (1.0f / ((float)BATCH * (float)HW));
    const float exact_sum  = a1;
    const float exact_frac = exact_sum * (1.0f / (float)BATCH);
    const float copy_pen   = 5.0f * a2 * (1.0f / (float)BATCH);
    const float tdiff      = a3 * (1.0f / (float)BATCH);
    const float color_pen  = 0.1f * a4;
    float total = ce_loss - exact_frac + copy_pen + tdiff + color_pen;
    if (isnan(total)) total = 2.0f;
    else if (total > 100.0f) total = 10.0f;
    out[0] = total;
    out[1] = ce_loss;
    out[2] = copy_pen;
    out[3] = exact_frac;
    out[4] = exact_sum;
    out[5] = tdiff;
  }
}

extern "C" void kernel_launch(void* const* d_in, const int* in_sizes, int n_in,
                              void* d_out, int out_size, void* d_ws, size_t ws_size,
                              hipStream_t stream) {
  const float* pred   = (const float*)d_in[0];
  const float* target = (const float*)d_in[1];
  const float* inp    = (const float*)d_in[2];
  float4* ws = (float4*)d_ws;  // 4096 slots * 16 B = 64 KB; fully written
                               // every launch before being read -> no memset.
  loss_main<<<dim3(BATCH * 4), dim3(256), 0, stream>>>(pred, target, inp, ws);
  loss_final<<<dim3(1), dim3(1024), 0, stream>>>(ws, (float*)d_out);
}